// Round 4
// baseline (694.690 us; speedup 1.0000x reference)
//
#include <hip/hip_runtime.h>

#define TPB 256

typedef __attribute__((ext_vector_type(8))) short short8;
typedef __attribute__((ext_vector_type(4))) float floatx4;

__device__ __forceinline__ unsigned short bf_trunc(float f){
    union { float f; unsigned u; } c; c.f = f;
    return (unsigned short)(c.u >> 16);
}
__device__ __forceinline__ unsigned short bf_rne(float f){
    union { float f; unsigned u; } c; c.f = f;
    unsigned r = c.u + 0x7fffu + ((c.u >> 16) & 1u);
    return (unsigned short)(r >> 16);
}

// ---------------------------------------------------------------------------
// pass1: transposed MFMA D = W^T * feats^T; per-channel stats (register
// accum), mask branch (relu -> dot -> 2 shfl), pooled per-batch sums.
// Depth-1 register prefetch: tile t+1's loads issue before tile t's compute,
// so the ~600-cyc L3/HBM latency overlaps MFMA+VALU work.
// ---------------------------------------------------------------------------
__global__ __launch_bounds__(TPB, 7) void pass1_kernel(
    const float* __restrict__ feats, const int* __restrict__ bidx,
    const float* __restrict__ w1, const float* __restrict__ b1,
    const float* __restrict__ mw1, const float* __restrict__ mb1,
    const float* __restrict__ mw2, const float* __restrict__ mb2,
    float* __restrict__ mask_out,
    float* __restrict__ ws_sum, float* __restrict__ ws_sq,
    float* __restrict__ ws_pool, int N)
{
    __shared__ float s_pool[8][32];
    __shared__ float s_sum[32];
    __shared__ float s_sq[32];

    const int tid  = threadIdx.x;
    const int lane = tid & 63;
    const int p = lane & 15;               // point-in-tile (MFMA col / A-row)
    const int q = lane >> 4;               // k-group

    if (tid < 32){ s_sum[tid] = 0.f; s_sq[tid] = 0.f; }
    ((float*)s_pool)[tid] = 0.f;
    __syncthreads();

    short8 aw0, aw1, am0, am1;
    floatx4 ci_h0, ci_h1, ci_m0, ci_m1;
    float mw2v[8];
#pragma unroll
    for (int j = 0; j < 8; ++j){
        const int k = q * 8 + j;
        aw0[j] = (short)bf_rne(w1 [k * 32 + p]);
        aw1[j] = (short)bf_rne(w1 [k * 32 + 16 + p]);
        am0[j] = (short)bf_rne(mw1[k * 32 + p]);
        am1[j] = (short)bf_rne(mw1[k * 32 + 16 + p]);
    }
#pragma unroll
    for (int r = 0; r < 4; ++r){
        const int c0 = q * 4 + r, c1 = 16 + q * 4 + r;
        ci_h0[r] = b1[c0];  ci_h1[r] = b1[c1];
        ci_m0[r] = mb1[c0]; ci_m1[r] = mb1[c1];
        mw2v[r] = mw2[c0];  mw2v[4 + r] = mw2[c1];
    }
    const float mb2s = mb2[0];

    float hsum[8] = {0,0,0,0,0,0,0,0};
    float hsq [8] = {0,0,0,0,0,0,0,0};
    float pacc[8] = {0,0,0,0,0,0,0,0};
    int curb = -1;

    const int  ntiles = (N + 15) >> 4;
    const long nw  = (long)gridDim.x * (TPB / 64);
    const long wid = (long)blockIdx.x * (TPB / 64) + (tid >> 6);
    const int  t0 = (int)(wid * (long)ntiles / nw);
    const int  t1 = (int)((wid + 1) * (long)ntiles / nw);

    // ---- prime the pipeline: tile t0 ----
    floatx4 v0 = {0.f,0.f,0.f,0.f}, v1 = {0.f,0.f,0.f,0.f};
    int b = -1;
    if (t0 < t1){
        const int row = (t0 << 4) + p;
        if (row < N){
            const floatx4* rp = (const floatx4*)(feats + (size_t)row * 32 + q * 8);
            v0 = rp[0]; v1 = rp[1];
            b  = bidx[row];
        }
    }

    for (int t = t0; t < t1; ++t){
        // ---- prefetch tile t+1 (independent of current processing) ----
        floatx4 nv0 = {0.f,0.f,0.f,0.f}, nv1 = {0.f,0.f,0.f,0.f};
        int nb = -1;
        if (t + 1 < t1){
            const int nrow = ((t + 1) << 4) + p;
            if (nrow < N){
                const floatx4* rp = (const floatx4*)(feats + (size_t)nrow * 32 + q * 8);
                nv0 = rp[0]; nv1 = rp[1];
                nb  = bidx[nrow];
            }
        }

        // ---- process current tile ----
        const bool valid = (b >= 0);
        if (b != curb){
            if (curb >= 0){
#pragma unroll
                for (int j = 0; j < 8; ++j){
                    atomicAdd(&s_pool[curb][q * 8 + j], pacc[j]);
                    pacc[j] = 0.f;
                }
            }
            curb = b;
        }
        if (valid){
            pacc[0] += v0[0]; pacc[1] += v0[1]; pacc[2] += v0[2]; pacc[3] += v0[3];
            pacc[4] += v1[0]; pacc[5] += v1[1]; pacc[6] += v1[2]; pacc[7] += v1[3];
        }

        short8 bfrag;
        bfrag[0] = (short)bf_trunc(v0[0]); bfrag[1] = (short)bf_trunc(v0[1]);
        bfrag[2] = (short)bf_trunc(v0[2]); bfrag[3] = (short)bf_trunc(v0[3]);
        bfrag[4] = (short)bf_trunc(v1[0]); bfrag[5] = (short)bf_trunc(v1[1]);
        bfrag[6] = (short)bf_trunc(v1[2]); bfrag[7] = (short)bf_trunc(v1[3]);

        const floatx4 ch0 = __builtin_amdgcn_mfma_f32_16x16x32_bf16(aw0, bfrag, ci_h0, 0, 0, 0);
        const floatx4 ch1 = __builtin_amdgcn_mfma_f32_16x16x32_bf16(aw1, bfrag, ci_h1, 0, 0, 0);
        const floatx4 cm0 = __builtin_amdgcn_mfma_f32_16x16x32_bf16(am0, bfrag, ci_m0, 0, 0, 0);
        const floatx4 cm1 = __builtin_amdgcn_mfma_f32_16x16x32_bf16(am1, bfrag, ci_m1, 0, 0, 0);

        if (valid){
#pragma unroll
            for (int r = 0; r < 4; ++r){
                const float h0 = ch0[r]; hsum[r]     += h0; hsq[r]     = fmaf(h0, h0, hsq[r]);
                const float h1 = ch1[r]; hsum[4 + r] += h1; hsq[4 + r] = fmaf(h1, h1, hsq[4 + r]);
            }
        }

        float tm = 0.f;
#pragma unroll
        for (int r = 0; r < 4; ++r){
            tm = fmaf(fmaxf(cm0[r], 0.f), mw2v[r],     tm);
            tm = fmaf(fmaxf(cm1[r], 0.f), mw2v[4 + r], tm);
        }
        tm += __shfl_xor(tm, 16, 64);
        tm += __shfl_xor(tm, 32, 64);
        if (q == 0 && valid) mask_out[(t << 4) + p] = tm + mb2s;

        // rotate
        v0 = nv0; v1 = nv1; b = nb;
    }

    if (curb >= 0){
#pragma unroll
        for (int j = 0; j < 8; ++j) atomicAdd(&s_pool[curb][q * 8 + j], pacc[j]);
    }
#pragma unroll
    for (int i = 0; i < 8; ++i){
        const int ch = (i >> 2) * 16 + q * 4 + (i & 3);
        atomicAdd(&s_sum[ch], hsum[i]);
        atomicAdd(&s_sq[ch],  hsq[i]);
    }
    __syncthreads();
    if (tid < 32){
        atomicAdd(&ws_sum[tid], s_sum[tid]);
        atomicAdd(&ws_sq[tid],  s_sq[tid]);
    }
    {
        const float pv = ((float*)s_pool)[tid];
        if (pv != 0.f) atomicAdd(&ws_pool[tid], pv);
    }
}

// ---------------------------------------------------------------------------
// pass2: every block recomputes the BN fold from global stats (32 channels,
// trivial; kernel boundary = the grid sync), block 0 also writes pooled+iou.
// Then folded-weight MFMA, relu, 32x3 projection with depth-1 prefetch.
// feats is L3-resident from pass1 -> ~300-cyc loads, no HBM refetch.
// ---------------------------------------------------------------------------
__global__ __launch_bounds__(TPB, 6) void pass2_kernel(
    const float* __restrict__ feats, const int* __restrict__ bidx,
    const float* __restrict__ w1, const float* __restrict__ b1,
    const float* __restrict__ gamma, const float* __restrict__ beta,
    const float* __restrict__ w2, const float* __restrict__ b2,
    const float* __restrict__ iw, const float* __restrict__ ib,
    const float* __restrict__ ws_sum, const float* __restrict__ ws_sq,
    const float* __restrict__ ws_pool,
    float* __restrict__ pt_out, float* __restrict__ pooled_out,
    float* __restrict__ iou_out, int N, int B)
{
    __shared__ float s_sc[32];
    __shared__ float s_bp[32];
    __shared__ float s_pooled[256];
    __shared__ int   s_lb[33];

    const int tid  = threadIdx.x;
    const int lane = tid & 63;
    const int p = lane & 15;
    const int q = lane >> 4;

    if (tid < 32){
        const float invN = 1.f / (float)N;
        const float mu  = ws_sum[tid] * invN;
        const float var = ws_sq[tid] * invN - mu * mu;
        const float s   = gamma[tid] * rsqrtf(var + 1e-4f);
        s_sc[tid] = s;
        s_bp[tid] = (b1[tid] - mu) * s + beta[tid];
    }
    __syncthreads();

    if (blockIdx.x == 0){
        if (tid <= B){
            int lo = 0, hi = N;
            while (lo < hi){
                const int mid = (lo + hi) >> 1;
                if (bidx[mid] < tid) lo = mid + 1; else hi = mid;
            }
            s_lb[tid] = lo;
        }
        __syncthreads();
        if (tid < B * 32){
            const int bb = tid >> 5;
            const float cnt = fmaxf((float)(s_lb[bb + 1] - s_lb[bb]), 1.f);
            const float pv = ws_pool[tid] / cnt;
            s_pooled[tid]   = pv;
            pooled_out[tid] = pv;
        }
        __syncthreads();
        if (tid < B){
            float acc = ib[0];
#pragma unroll
            for (int i = 0; i < 32; ++i) acc = fmaf(s_pooled[tid * 32 + i], iw[i], acc);
            iou_out[tid] = acc;
        }
    }

    short8 pw0, pw1;
    floatx4 pc0, pc1;
    float w2v[24];
    const float sc0 = s_sc[p], sc1 = s_sc[16 + p];
#pragma unroll
    for (int j = 0; j < 8; ++j){
        const int k = q * 8 + j;
        pw0[j] = (short)bf_rne(w1[k * 32 + p]      * sc0);
        pw1[j] = (short)bf_rne(w1[k * 32 + 16 + p] * sc1);
    }
#pragma unroll
    for (int r = 0; r < 4; ++r){
        pc0[r] = s_bp[q * 4 + r];
        pc1[r] = s_bp[16 + q * 4 + r];
    }
#pragma unroll
    for (int i = 0; i < 8; ++i){
        const int ch = (i >> 2) * 16 + q * 4 + (i & 3);
        w2v[i]      = w2[ch * 3 + 0];
        w2v[8 + i]  = w2[ch * 3 + 1];
        w2v[16 + i] = w2[ch * 3 + 2];
    }
    const float b2v0 = b2[0], b2v1 = b2[1], b2v2 = b2[2];

    const int  ntiles = (N + 15) >> 4;
    const long nw  = (long)gridDim.x * (TPB / 64);
    const long wid = (long)blockIdx.x * (TPB / 64) + (tid >> 6);
    const int  t0 = (int)(wid * (long)ntiles / nw);
    const int  t1 = (int)((wid + 1) * (long)ntiles / nw);

    floatx4 v0 = {0.f,0.f,0.f,0.f}, v1 = {0.f,0.f,0.f,0.f};
    bool valid = false;
    if (t0 < t1){
        const int row = (t0 << 4) + p;
        if (row < N){
            const floatx4* rp = (const floatx4*)(feats + (size_t)row * 32 + q * 8);
            v0 = rp[0]; v1 = rp[1];
            valid = true;
        }
    }

    for (int t = t0; t < t1; ++t){
        floatx4 nv0 = {0.f,0.f,0.f,0.f}, nv1 = {0.f,0.f,0.f,0.f};
        bool nvalid = false;
        if (t + 1 < t1){
            const int nrow = ((t + 1) << 4) + p;
            if (nrow < N){
                const floatx4* rp = (const floatx4*)(feats + (size_t)nrow * 32 + q * 8);
                nv0 = rp[0]; nv1 = rp[1];
                nvalid = true;
            }
        }

        short8 bfrag;
        bfrag[0] = (short)bf_trunc(v0[0]); bfrag[1] = (short)bf_trunc(v0[1]);
        bfrag[2] = (short)bf_trunc(v0[2]); bfrag[3] = (short)bf_trunc(v0[3]);
        bfrag[4] = (short)bf_trunc(v1[0]); bfrag[5] = (short)bf_trunc(v1[1]);
        bfrag[6] = (short)bf_trunc(v1[2]); bfrag[7] = (short)bf_trunc(v1[3]);

        const floatx4 c0 = __builtin_amdgcn_mfma_f32_16x16x32_bf16(pw0, bfrag, pc0, 0, 0, 0);
        const floatx4 c1 = __builtin_amdgcn_mfma_f32_16x16x32_bf16(pw1, bfrag, pc1, 0, 0, 0);

        float s0 = 0.f, s1 = 0.f, s2 = 0.f;
#pragma unroll
        for (int r = 0; r < 4; ++r){
            const float p0 = fmaxf(c0[r], 0.f);
            const float p1 = fmaxf(c1[r], 0.f);
            s0 = fmaf(p0, w2v[r],      s0); s0 = fmaf(p1, w2v[4 + r],  s0);
            s1 = fmaf(p0, w2v[8 + r],  s1); s1 = fmaf(p1, w2v[12 + r], s1);
            s2 = fmaf(p0, w2v[16 + r], s2); s2 = fmaf(p1, w2v[20 + r], s2);
        }
        s0 += __shfl_xor(s0, 16, 64); s0 += __shfl_xor(s0, 32, 64);
        s1 += __shfl_xor(s1, 16, 64); s1 += __shfl_xor(s1, 32, 64);
        s2 += __shfl_xor(s2, 16, 64); s2 += __shfl_xor(s2, 32, 64);

        if (lane < 48 && valid){
            float val = (q == 0) ? (s0 + b2v0) : ((q == 1) ? (s1 + b2v1) : (s2 + b2v2));
            pt_out[(size_t)(t << 4) * 3 + p * 3 + q] = val;
        }

        v0 = nv0; v1 = nv1; valid = nvalid;
    }
}

extern "C" void kernel_launch(void* const* d_in, const int* in_sizes, int n_in,
                              void* d_out, int out_size, void* d_ws, size_t ws_size,
                              hipStream_t stream) {
    const float* feats = (const float*)d_in[0];
    const int*   bidx  = (const int*)d_in[1];
    const float* w1    = (const float*)d_in[2];
    const float* b1    = (const float*)d_in[3];
    const float* gamma = (const float*)d_in[4];
    const float* beta  = (const float*)d_in[5];
    const float* w2    = (const float*)d_in[6];
    const float* b2    = (const float*)d_in[7];
    const float* mw1   = (const float*)d_in[8];
    const float* mb1   = (const float*)d_in[9];
    const float* mw2   = (const float*)d_in[10];
    const float* mb2   = (const float*)d_in[11];
    const float* iw    = (const float*)d_in[12];
    const float* ib    = (const float*)d_in[13];

    const int N = in_sizes[0] / 32;
    const int B = (out_size - 4 * N) / 33;   // out = 3N + N + 32B + B

    float* out    = (float*)d_out;
    float* pt     = out;                       // [N,3]
    float* mask   = out + (size_t)3 * N;       // [N,1]
    float* pooled = out + (size_t)4 * N;       // [B,32]
    float* iou    = pooled + (size_t)B * 32;   // [B,1]

    float* ws      = (float*)d_ws;
    float* ws_sum  = ws;                 // 32
    float* ws_sq   = ws + 32;            // 32
    float* ws_pool = ws + 64;            // B*32

    hipMemsetAsync(ws, 0, (size_t)(64 + B * 32) * sizeof(float), stream);

    // 7 blocks/CU * 256 CU co-resident; grid matched so each wave owns one
    // contiguous span (pass1) — pass2 spans align for L2/L3 locality.
    pass1_kernel<<<1792, TPB, 0, stream>>>(feats, bidx, w1, b1, mw1, mb1, mw2, mb2,
                                           mask, ws_sum, ws_sq, ws_pool, N);
    pass2_kernel<<<1536, TPB, 0, stream>>>(feats, bidx, w1, b1, gamma, beta, w2, b2,
                                           iw, ib, ws_sum, ws_sq, ws_pool,
                                           pt, pooled, iou, N, B);
}

// Round 5
// 457.359 us; speedup vs baseline: 1.5189x; 1.5189x over previous
//
#include <hip/hip_runtime.h>

#define TPB 256

typedef __attribute__((ext_vector_type(8))) short short8;
typedef __attribute__((ext_vector_type(4))) float floatx4;

__device__ __forceinline__ unsigned short bf_trunc(float f){
    union { float f; unsigned u; } c; c.f = f;
    return (unsigned short)(c.u >> 16);
}
__device__ __forceinline__ unsigned short bf_rne(float f){
    union { float f; unsigned u; } c; c.f = f;
    unsigned r = c.u + 0x7fffu + ((c.u >> 16) & 1u);
    return (unsigned short)(r >> 16);
}

// ---------------------------------------------------------------------------
// pass1: transposed MFMA D = W^T * feats^T; per-channel stats (register
// accum), mask branch (relu -> dot -> 2 shfl), pooled per-batch sums.
// Depth-1 register prefetch. launch_bounds(,4): VGPR cap 128 -- R4's cap of
// 73 caused ~800 MB of scratch spill traffic; working set is ~90 VGPRs.
// ---------------------------------------------------------------------------
__global__ __launch_bounds__(TPB, 4) void pass1_kernel(
    const float* __restrict__ feats, const int* __restrict__ bidx,
    const float* __restrict__ w1, const float* __restrict__ b1,
    const float* __restrict__ mw1, const float* __restrict__ mb1,
    const float* __restrict__ mw2, const float* __restrict__ mb2,
    float* __restrict__ mask_out,
    float* __restrict__ ws_sum, float* __restrict__ ws_sq,
    float* __restrict__ ws_pool, int N)
{
    __shared__ float s_pool[8][32];
    __shared__ float s_sum[32];
    __shared__ float s_sq[32];

    const int tid  = threadIdx.x;
    const int lane = tid & 63;
    const int p = lane & 15;               // point-in-tile (MFMA col / A-row)
    const int q = lane >> 4;               // k-group

    if (tid < 32){ s_sum[tid] = 0.f; s_sq[tid] = 0.f; }
    ((float*)s_pool)[tid] = 0.f;
    __syncthreads();

    short8 aw0, aw1, am0, am1;
    floatx4 ci_h0, ci_h1, ci_m0, ci_m1;
    float mw2v[8];
#pragma unroll
    for (int j = 0; j < 8; ++j){
        const int k = q * 8 + j;
        aw0[j] = (short)bf_rne(w1 [k * 32 + p]);
        aw1[j] = (short)bf_rne(w1 [k * 32 + 16 + p]);
        am0[j] = (short)bf_rne(mw1[k * 32 + p]);
        am1[j] = (short)bf_rne(mw1[k * 32 + 16 + p]);
    }
#pragma unroll
    for (int r = 0; r < 4; ++r){
        const int c0 = q * 4 + r, c1 = 16 + q * 4 + r;
        ci_h0[r] = b1[c0];  ci_h1[r] = b1[c1];
        ci_m0[r] = mb1[c0]; ci_m1[r] = mb1[c1];
        mw2v[r] = mw2[c0];  mw2v[4 + r] = mw2[c1];
    }
    const float mb2s = mb2[0];

    float hsum[8] = {0,0,0,0,0,0,0,0};
    float hsq [8] = {0,0,0,0,0,0,0,0};
    float pacc[8] = {0,0,0,0,0,0,0,0};
    int curb = -1;

    const int  ntiles = (N + 15) >> 4;
    const long nw  = (long)gridDim.x * (TPB / 64);
    const long wid = (long)blockIdx.x * (TPB / 64) + (tid >> 6);
    const int  t0 = (int)(wid * (long)ntiles / nw);
    const int  t1 = (int)((wid + 1) * (long)ntiles / nw);

    // prime tile t0
    floatx4 v0 = {0.f,0.f,0.f,0.f}, v1 = {0.f,0.f,0.f,0.f};
    int b = -1;
    if (t0 < t1){
        const int row = (t0 << 4) + p;
        if (row < N){
            const floatx4* rp = (const floatx4*)(feats + (size_t)row * 32 + q * 8);
            v0 = rp[0]; v1 = rp[1];
            b  = bidx[row];
        }
    }

    for (int t = t0; t < t1; ++t){
        // prefetch tile t+1
        floatx4 nv0 = {0.f,0.f,0.f,0.f}, nv1 = {0.f,0.f,0.f,0.f};
        int nb = -1;
        if (t + 1 < t1){
            const int nrow = ((t + 1) << 4) + p;
            if (nrow < N){
                const floatx4* rp = (const floatx4*)(feats + (size_t)nrow * 32 + q * 8);
                nv0 = rp[0]; nv1 = rp[1];
                nb  = bidx[nrow];
            }
        }

        const bool valid = (b >= 0);
        if (b != curb){
            if (curb >= 0){
#pragma unroll
                for (int j = 0; j < 8; ++j){
                    atomicAdd(&s_pool[curb][q * 8 + j], pacc[j]);
                    pacc[j] = 0.f;
                }
            }
            curb = b;
        }
        if (valid){
            pacc[0] += v0[0]; pacc[1] += v0[1]; pacc[2] += v0[2]; pacc[3] += v0[3];
            pacc[4] += v1[0]; pacc[5] += v1[1]; pacc[6] += v1[2]; pacc[7] += v1[3];
        }

        short8 bfrag;
        bfrag[0] = (short)bf_trunc(v0[0]); bfrag[1] = (short)bf_trunc(v0[1]);
        bfrag[2] = (short)bf_trunc(v0[2]); bfrag[3] = (short)bf_trunc(v0[3]);
        bfrag[4] = (short)bf_trunc(v1[0]); bfrag[5] = (short)bf_trunc(v1[1]);
        bfrag[6] = (short)bf_trunc(v1[2]); bfrag[7] = (short)bf_trunc(v1[3]);

        const floatx4 ch0 = __builtin_amdgcn_mfma_f32_16x16x32_bf16(aw0, bfrag, ci_h0, 0, 0, 0);
        const floatx4 ch1 = __builtin_amdgcn_mfma_f32_16x16x32_bf16(aw1, bfrag, ci_h1, 0, 0, 0);
        const floatx4 cm0 = __builtin_amdgcn_mfma_f32_16x16x32_bf16(am0, bfrag, ci_m0, 0, 0, 0);
        const floatx4 cm1 = __builtin_amdgcn_mfma_f32_16x16x32_bf16(am1, bfrag, ci_m1, 0, 0, 0);

        if (valid){
#pragma unroll
            for (int r = 0; r < 4; ++r){
                const float h0 = ch0[r]; hsum[r]     += h0; hsq[r]     = fmaf(h0, h0, hsq[r]);
                const float h1 = ch1[r]; hsum[4 + r] += h1; hsq[4 + r] = fmaf(h1, h1, hsq[4 + r]);
            }
        }

        float tm = 0.f;
#pragma unroll
        for (int r = 0; r < 4; ++r){
            tm = fmaf(fmaxf(cm0[r], 0.f), mw2v[r],     tm);
            tm = fmaf(fmaxf(cm1[r], 0.f), mw2v[4 + r], tm);
        }
        tm += __shfl_xor(tm, 16, 64);
        tm += __shfl_xor(tm, 32, 64);
        if (q == 0 && valid) mask_out[(t << 4) + p] = tm + mb2s;

        v0 = nv0; v1 = nv1; b = nb;
    }

    if (curb >= 0){
#pragma unroll
        for (int j = 0; j < 8; ++j) atomicAdd(&s_pool[curb][q * 8 + j], pacc[j]);
    }
#pragma unroll
    for (int i = 0; i < 8; ++i){
        const int ch = (i >> 2) * 16 + q * 4 + (i & 3);
        atomicAdd(&s_sum[ch], hsum[i]);
        atomicAdd(&s_sq[ch],  hsq[i]);
    }
    __syncthreads();
    if (tid < 32){
        atomicAdd(&ws_sum[tid], s_sum[tid]);
        atomicAdd(&ws_sq[tid],  s_sq[tid]);
    }
    {
        const float pv = ((float*)s_pool)[tid];
        if (pv != 0.f) atomicAdd(&ws_pool[tid], pv);
    }
}

// ---------------------------------------------------------------------------
// pass2: per-block BN fold from global stats (kernel boundary = grid sync),
// block 0 writes pooled+iou; folded-weight MFMA, relu, 32x3 projection with
// depth-1 prefetch. feats is L3-resident from pass1.
// ---------------------------------------------------------------------------
__global__ __launch_bounds__(TPB, 4) void pass2_kernel(
    const float* __restrict__ feats, const int* __restrict__ bidx,
    const float* __restrict__ w1, const float* __restrict__ b1,
    const float* __restrict__ gamma, const float* __restrict__ beta,
    const float* __restrict__ w2, const float* __restrict__ b2,
    const float* __restrict__ iw, const float* __restrict__ ib,
    const float* __restrict__ ws_sum, const float* __restrict__ ws_sq,
    const float* __restrict__ ws_pool,
    float* __restrict__ pt_out, float* __restrict__ pooled_out,
    float* __restrict__ iou_out, int N, int B)
{
    __shared__ float s_sc[32];
    __shared__ float s_bp[32];
    __shared__ float s_pooled[256];
    __shared__ int   s_lb[33];

    const int tid  = threadIdx.x;
    const int lane = tid & 63;
    const int p = lane & 15;
    const int q = lane >> 4;

    if (tid < 32){
        const float invN = 1.f / (float)N;
        const float mu  = ws_sum[tid] * invN;
        const float var = ws_sq[tid] * invN - mu * mu;
        const float s   = gamma[tid] * rsqrtf(var + 1e-4f);
        s_sc[tid] = s;
        s_bp[tid] = (b1[tid] - mu) * s + beta[tid];
    }
    __syncthreads();

    if (blockIdx.x == 0){
        if (tid <= B){
            int lo = 0, hi = N;
            while (lo < hi){
                const int mid = (lo + hi) >> 1;
                if (bidx[mid] < tid) lo = mid + 1; else hi = mid;
            }
            s_lb[tid] = lo;
        }
        __syncthreads();
        if (tid < B * 32){
            const int bb = tid >> 5;
            const float cnt = fmaxf((float)(s_lb[bb + 1] - s_lb[bb]), 1.f);
            const float pv = ws_pool[tid] / cnt;
            s_pooled[tid]   = pv;
            pooled_out[tid] = pv;
        }
        __syncthreads();
        if (tid < B){
            float acc = ib[0];
#pragma unroll
            for (int i = 0; i < 32; ++i) acc = fmaf(s_pooled[tid * 32 + i], iw[i], acc);
            iou_out[tid] = acc;
        }
    }

    short8 pw0, pw1;
    floatx4 pc0, pc1;
    float w2v[24];
    const float sc0 = s_sc[p], sc1 = s_sc[16 + p];
#pragma unroll
    for (int j = 0; j < 8; ++j){
        const int k = q * 8 + j;
        pw0[j] = (short)bf_rne(w1[k * 32 + p]      * sc0);
        pw1[j] = (short)bf_rne(w1[k * 32 + 16 + p] * sc1);
    }
#pragma unroll
    for (int r = 0; r < 4; ++r){
        pc0[r] = s_bp[q * 4 + r];
        pc1[r] = s_bp[16 + q * 4 + r];
    }
#pragma unroll
    for (int i = 0; i < 8; ++i){
        const int ch = (i >> 2) * 16 + q * 4 + (i & 3);
        w2v[i]      = w2[ch * 3 + 0];
        w2v[8 + i]  = w2[ch * 3 + 1];
        w2v[16 + i] = w2[ch * 3 + 2];
    }
    const float b2v0 = b2[0], b2v1 = b2[1], b2v2 = b2[2];

    const int  ntiles = (N + 15) >> 4;
    const long nw  = (long)gridDim.x * (TPB / 64);
    const long wid = (long)blockIdx.x * (TPB / 64) + (tid >> 6);
    const int  t0 = (int)(wid * (long)ntiles / nw);
    const int  t1 = (int)((wid + 1) * (long)ntiles / nw);

    floatx4 v0 = {0.f,0.f,0.f,0.f}, v1 = {0.f,0.f,0.f,0.f};
    bool valid = false;
    if (t0 < t1){
        const int row = (t0 << 4) + p;
        if (row < N){
            const floatx4* rp = (const floatx4*)(feats + (size_t)row * 32 + q * 8);
            v0 = rp[0]; v1 = rp[1];
            valid = true;
        }
    }

    for (int t = t0; t < t1; ++t){
        floatx4 nv0 = {0.f,0.f,0.f,0.f}, nv1 = {0.f,0.f,0.f,0.f};
        bool nvalid = false;
        if (t + 1 < t1){
            const int nrow = ((t + 1) << 4) + p;
            if (nrow < N){
                const floatx4* rp = (const floatx4*)(feats + (size_t)nrow * 32 + q * 8);
                nv0 = rp[0]; nv1 = rp[1];
                nvalid = true;
            }
        }

        short8 bfrag;
        bfrag[0] = (short)bf_trunc(v0[0]); bfrag[1] = (short)bf_trunc(v0[1]);
        bfrag[2] = (short)bf_trunc(v0[2]); bfrag[3] = (short)bf_trunc(v0[3]);
        bfrag[4] = (short)bf_trunc(v1[0]); bfrag[5] = (short)bf_trunc(v1[1]);
        bfrag[6] = (short)bf_trunc(v1[2]); bfrag[7] = (short)bf_trunc(v1[3]);

        const floatx4 c0 = __builtin_amdgcn_mfma_f32_16x16x32_bf16(pw0, bfrag, pc0, 0, 0, 0);
        const floatx4 c1 = __builtin_amdgcn_mfma_f32_16x16x32_bf16(pw1, bfrag, pc1, 0, 0, 0);

        float s0 = 0.f, s1 = 0.f, s2 = 0.f;
#pragma unroll
        for (int r = 0; r < 4; ++r){
            const float p0 = fmaxf(c0[r], 0.f);
            const float p1 = fmaxf(c1[r], 0.f);
            s0 = fmaf(p0, w2v[r],      s0); s0 = fmaf(p1, w2v[4 + r],  s0);
            s1 = fmaf(p0, w2v[8 + r],  s1); s1 = fmaf(p1, w2v[12 + r], s1);
            s2 = fmaf(p0, w2v[16 + r], s2); s2 = fmaf(p1, w2v[20 + r], s2);
        }
        s0 += __shfl_xor(s0, 16, 64); s0 += __shfl_xor(s0, 32, 64);
        s1 += __shfl_xor(s1, 16, 64); s1 += __shfl_xor(s1, 32, 64);
        s2 += __shfl_xor(s2, 16, 64); s2 += __shfl_xor(s2, 32, 64);

        if (lane < 48 && valid){
            float val = (q == 0) ? (s0 + b2v0) : ((q == 1) ? (s1 + b2v1) : (s2 + b2v2));
            pt_out[(size_t)(t << 4) * 3 + p * 3 + q] = val;
        }

        v0 = nv0; v1 = nv1; valid = nvalid;
    }
}

extern "C" void kernel_launch(void* const* d_in, const int* in_sizes, int n_in,
                              void* d_out, int out_size, void* d_ws, size_t ws_size,
                              hipStream_t stream) {
    const float* feats = (const float*)d_in[0];
    const int*   bidx  = (const int*)d_in[1];
    const float* w1    = (const float*)d_in[2];
    const float* b1    = (const float*)d_in[3];
    const float* gamma = (const float*)d_in[4];
    const float* beta  = (const float*)d_in[5];
    const float* w2    = (const float*)d_in[6];
    const float* b2    = (const float*)d_in[7];
    const float* mw1   = (const float*)d_in[8];
    const float* mb1   = (const float*)d_in[9];
    const float* mw2   = (const float*)d_in[10];
    const float* mb2   = (const float*)d_in[11];
    const float* iw    = (const float*)d_in[12];
    const float* ib    = (const float*)d_in[13];

    const int N = in_sizes[0] / 32;
    const int B = (out_size - 4 * N) / 33;   // out = 3N + N + 32B + B

    float* out    = (float*)d_out;
    float* pt     = out;                       // [N,3]
    float* mask   = out + (size_t)3 * N;       // [N,1]
    float* pooled = out + (size_t)4 * N;       // [B,32]
    float* iou    = pooled + (size_t)B * 32;   // [B,1]

    float* ws      = (float*)d_ws;
    float* ws_sum  = ws;                 // 32
    float* ws_sq   = ws + 32;            // 32
    float* ws_pool = ws + 64;            // B*32

    hipMemsetAsync(ws, 0, (size_t)(64 + B * 32) * sizeof(float), stream);

    // co-resident grids sized from the occupancy API (adapts to VGPR count)
    int dev = 0;
    hipGetDevice(&dev);
    hipDeviceProp_t prop;
    hipGetDeviceProperties(&prop, dev);
    int per1 = 0, per2 = 0;
    hipOccupancyMaxActiveBlocksPerMultiprocessor(&per1, pass1_kernel, TPB, 0);
    hipOccupancyMaxActiveBlocksPerMultiprocessor(&per2, pass2_kernel, TPB, 0);
    int g1 = per1 * prop.multiProcessorCount; if (g1 < 256) g1 = 256;
    int g2 = per2 * prop.multiProcessorCount; if (g2 < 256) g2 = 256;

    pass1_kernel<<<g1, TPB, 0, stream>>>(feats, bidx, w1, b1, mw1, mb1, mw2, mb2,
                                         mask, ws_sum, ws_sq, ws_pool, N);
    pass2_kernel<<<g2, TPB, 0, stream>>>(feats, bidx, w1, b1, gamma, beta, w2, b2,
                                         iw, ib, ws_sum, ws_sq, ws_pool,
                                         pt, pooled, iou, N, B);
}